// Round 3
// baseline (296.311 us; speedup 1.0000x reference)
//
#include <hip/hip_runtime.h>

#define BB 2
#define NN 4096
#define CC 32
#define DPAD 100   // 33*3 = 99 real dims + 1 zero pad -> float4-aligned rows
#define TILE 64

// ---------------- prep: build X [B,N,100], Y-rotated [B,N,100], row norms ----
__global__ __launch_bounds__(256) void prep_kernel(
    const float* __restrict__ pc1, const float* __restrict__ pc2,
    const float* __restrict__ xfeat, const float* __restrict__ yfeat,
    const float* __restrict__ quat,
    float* __restrict__ xf, float* __restrict__ yf,
    float* __restrict__ xn, float* __restrict__ yn,
    float* __restrict__ out)
{
    int idx = blockIdx.x * blockDim.x + threadIdx.x;
    if (idx == 0) out[0] = 0.f;          // sum accumulator (d_out poisoned 0xAA)
    if (idx >= BB * NN) return;
    int b = idx / NN, n = idx % NN;

    // pypose SO3 quat (x,y,z,w) -> rotmat
    float qx = quat[b*4+0], qy = quat[b*4+1], qz = quat[b*4+2], qw = quat[b*4+3];
    float qn = rsqrtf(qx*qx + qy*qy + qz*qz + qw*qw);
    qx *= qn; qy *= qn; qz *= qn; qw *= qn;
    float r00 = 1.f-2.f*(qy*qy+qz*qz), r01 = 2.f*(qx*qy-qz*qw), r02 = 2.f*(qx*qz+qy*qw);
    float r10 = 2.f*(qx*qy+qz*qw), r11 = 1.f-2.f*(qx*qx+qz*qz), r12 = 2.f*(qy*qz-qx*qw);
    float r20 = 2.f*(qx*qz-qy*qw), r21 = 2.f*(qy*qz+qx*qw), r22 = 1.f-2.f*(qx*qx+qy*qy);

    float* xrow = xf + (size_t)idx * DPAD;
    float* yrow = yf + (size_t)idx * DPAD;
    float sx = 0.f, sy = 0.f;

    // channel 0: raw coords
    {
        float v0 = pc1[(b*3+0)*NN + n], v1 = pc1[(b*3+1)*NN + n], v2 = pc1[(b*3+2)*NN + n];
        xrow[0] = v0; xrow[1] = v1; xrow[2] = v2;
        sx += v0*v0 + v1*v1 + v2*v2;
        float u0 = pc2[(b*3+0)*NN + n], u1 = pc2[(b*3+1)*NN + n], u2 = pc2[(b*3+2)*NN + n];
        float w0 = r00*u0 + r01*u1 + r02*u2;
        float w1 = r10*u0 + r11*u1 + r12*u2;
        float w2 = r20*u0 + r21*u1 + r22*u2;
        yrow[0] = w0; yrow[1] = w1; yrow[2] = w2;
        sy += w0*w0 + w1*w1 + w2*w2;
    }
    // channels 1..32: features  (layout [B,C,3,N])
    for (int c = 0; c < CC; ++c) {
        size_t base = ((size_t)(b*CC + c) * 3) * NN + n;
        int d = (c + 1) * 3;
        float v0 = xfeat[base], v1 = xfeat[base + NN], v2 = xfeat[base + 2*NN];
        xrow[d] = v0; xrow[d+1] = v1; xrow[d+2] = v2;
        sx += v0*v0 + v1*v1 + v2*v2;
        float u0 = yfeat[base], u1 = yfeat[base + NN], u2 = yfeat[base + 2*NN];
        float w0 = r00*u0 + r01*u1 + r02*u2;
        float w1 = r10*u0 + r11*u1 + r12*u2;
        float w2 = r20*u0 + r21*u1 + r22*u2;
        yrow[d] = w0; yrow[d+1] = w1; yrow[d+2] = w2;
        sy += w0*w0 + w1*w1 + w2*w2;
    }
    xrow[99] = 0.f; yrow[99] = 0.f;
    xn[idx] = sx; yn[idx] = sy;
}

// ---------------- main: 64x64 tile per block, full K staged in LDS ----------
__global__ __launch_bounds__(256) void gram_kernel(
    const float* __restrict__ xf, const float* __restrict__ yf,
    const float* __restrict__ xn, const float* __restrict__ yn,
    float* __restrict__ out)
{
    __shared__ __align__(16) float Xs[TILE * DPAD];
    __shared__ __align__(16) float Ys[TILE * DPAD];
    __shared__ float red[4];

    int b  = blockIdx.z;
    int tM = blockIdx.x * TILE;   // column (y / m) tile
    int tN = blockIdx.y * TILE;   // row (x / n) tile
    int tid = threadIdx.x;

    // both tiles are contiguous 6400-float blocks in global (LD == DPAD)
    const float4* xg = (const float4*)(xf + (size_t)(b*NN + tN) * DPAD);
    const float4* yg = (const float4*)(yf + (size_t)(b*NN + tM) * DPAD);
    float4* Xs4 = (float4*)Xs;
    float4* Ys4 = (float4*)Ys;
    #pragma unroll
    for (int i = tid; i < TILE*DPAD/4; i += 256) { Xs4[i] = xg[i]; Ys4[i] = yg[i]; }
    __syncthreads();

    int tx = tid & 15;   // m-quad  (coalesced stores along m)
    int ty = tid >> 4;   // n-quad
    float acc[4][4] = {};
    for (int k = 0; k < DPAD; k += 4) {
        float4 xv[4], yv[4];
        #pragma unroll
        for (int i = 0; i < 4; ++i) xv[i] = *(const float4*)&Xs[(ty*4+i)*DPAD + k];
        #pragma unroll
        for (int j = 0; j < 4; ++j) yv[j] = *(const float4*)&Ys[(tx*4+j)*DPAD + k];
        #pragma unroll
        for (int i = 0; i < 4; ++i)
            #pragma unroll
            for (int j = 0; j < 4; ++j)
                acc[i][j] += xv[i].x*yv[j].x + xv[i].y*yv[j].y
                           + xv[i].z*yv[j].z + xv[i].w*yv[j].w;
    }

    float xnv[4], ynv[4];
    #pragma unroll
    for (int i = 0; i < 4; ++i) xnv[i] = xn[b*NN + tN + ty*4 + i];
    #pragma unroll
    for (int j = 0; j < 4; ++j) ynv[j] = yn[b*NN + tM + tx*4 + j];

    const float inv2l2 = 0.005f;   // 1/(2*10*10)
    float lsum = 0.f;
    #pragma unroll
    for (int i = 0; i < 4; ++i) {
        size_t orow = 1 + (size_t)(b*NN + tN + ty*4 + i) * NN + tM + tx*4;
        #pragma unroll
        for (int j = 0; j < 4; ++j) {
            float sq = xnv[i] + ynv[j] - 2.f * acc[i][j];
            float g = __expf(-fmaxf(sq, 0.f) * inv2l2);
            g = (g > 0.1f) ? g : 0.f;
            out[orow + j] = g;
            lsum += g;
        }
    }

    // block reduction -> one atomic per block
    #pragma unroll
    for (int off = 32; off > 0; off >>= 1) lsum += __shfl_down(lsum, off, 64);
    int wid = tid >> 6, lane = tid & 63;
    if (lane == 0) red[wid] = lsum;
    __syncthreads();
    if (tid == 0) atomicAdd(out, red[0] + red[1] + red[2] + red[3]);
}

extern "C" void kernel_launch(void* const* d_in, const int* in_sizes, int n_in,
                              void* d_out, int out_size, void* d_ws, size_t ws_size,
                              hipStream_t stream) {
    const float* pc1   = (const float*)d_in[0];
    const float* pc2   = (const float*)d_in[1];
    const float* xfeat = (const float*)d_in[2];
    const float* yfeat = (const float*)d_in[3];
    const float* quat  = (const float*)d_in[4];
    float* out = (float*)d_out;

    float* xf = (float*)d_ws;
    float* yf = xf + (size_t)BB*NN*DPAD;
    float* xn = yf + (size_t)BB*NN*DPAD;
    float* yn = xn + (size_t)BB*NN;

    prep_kernel<<<(BB*NN + 255)/256, 256, 0, stream>>>(
        pc1, pc2, xfeat, yfeat, quat, xf, yf, xn, yn, out);

    dim3 grid(NN/TILE, NN/TILE, BB);
    gram_kernel<<<grid, 256, 0, stream>>>(xf, yf, xn, yn, out);
}

// Round 6
// 241.508 us; speedup vs baseline: 1.2269x; 1.2269x over previous
//
#include <hip/hip_runtime.h>
#include <hip/hip_bf16.h>

#define BB 2
#define NN 4096
#define CC 32

typedef __attribute__((ext_vector_type(8))) short short8;
typedef __attribute__((ext_vector_type(4))) float f32x4;

// Panel layout (bf16): per (b, n16, kb) a 1024B chunk; within it element
// (r = n&15, ksub = (k>>3)&3, kk = k&7) sits at short offset (ksub*16 + r)*8 + kk.
// => MFMA fragment load for 16x16x32: lane l reads 16B at chunk + l*16  (fully coalesced)
__device__ __forceinline__ size_t chunk_off(int b, int n16, int kb) {
    return (((size_t)b * 256 + n16) * 4 + kb) * 512;
}

__device__ __forceinline__ void store_el(__hip_bfloat16* P, int b, int n, int k, float v) {
    int kb = k >> 5, ks = (k >> 3) & 3, kk = k & 7;
    size_t off = chunk_off(b, n >> 4, kb) + (size_t)((ks * 16 + (n & 15)) * 8 + kk);
    P[off] = __float2bfloat16(v);
}

// ---------------- zero norms + sum slot ----------------
__global__ __launch_bounds__(256) void zero_kernel(float* xn, float* yn, float* out) {
    int i = blockIdx.x * 256 + threadIdx.x;
    if (i < BB * NN) { xn[i] = 0.f; yn[i] = 0.f; }
    if (i == 0) out[0] = 0.f;
}

// ---------------- prep: thread per (channel, b, n); c=0 is the coord channel ----
__global__ __launch_bounds__(256) void prep_kernel(
    const float* __restrict__ pc1, const float* __restrict__ pc2,
    const float* __restrict__ xfeat, const float* __restrict__ yfeat,
    const float* __restrict__ quat,
    __hip_bfloat16* __restrict__ Xp, __hip_bfloat16* __restrict__ Yp,
    float* __restrict__ xn, float* __restrict__ yn)
{
    int idx = blockIdx.x * 256 + threadIdx.x;
    if (idx >= BB * NN * (CC + 1)) return;
    int c = idx / (BB * NN);          // slowest: channel -> n stays coalesced
    int rem = idx - c * (BB * NN);
    int b = rem / NN, n = rem % NN;

    // quat (x,y,z,w) -> R
    float qx = quat[b*4+0], qy = quat[b*4+1], qz = quat[b*4+2], qw = quat[b*4+3];
    float qi = rsqrtf(qx*qx + qy*qy + qz*qz + qw*qw);
    qx *= qi; qy *= qi; qz *= qi; qw *= qi;
    float r00 = 1.f-2.f*(qy*qy+qz*qz), r01 = 2.f*(qx*qy-qz*qw), r02 = 2.f*(qx*qz+qy*qw);
    float r10 = 2.f*(qx*qy+qz*qw), r11 = 1.f-2.f*(qx*qx+qz*qz), r12 = 2.f*(qy*qz-qx*qw);
    float r20 = 2.f*(qx*qz-qy*qw), r21 = 2.f*(qy*qz+qx*qw), r22 = 1.f-2.f*(qx*qx+qy*qy);

    float v0, v1, v2, u0, u1, u2;
    if (c == 0) {
        v0 = pc1[(b*3+0)*NN + n]; v1 = pc1[(b*3+1)*NN + n]; v2 = pc1[(b*3+2)*NN + n];
        u0 = pc2[(b*3+0)*NN + n]; u1 = pc2[(b*3+1)*NN + n]; u2 = pc2[(b*3+2)*NN + n];
    } else {
        size_t base = ((size_t)(b*CC + (c-1)) * 3) * NN + n;
        v0 = xfeat[base]; v1 = xfeat[base + NN]; v2 = xfeat[base + 2*NN];
        u0 = yfeat[base]; u1 = yfeat[base + NN]; u2 = yfeat[base + 2*NN];
    }
    float w0 = r00*u0 + r01*u1 + r02*u2;
    float w1 = r10*u0 + r11*u1 + r12*u2;
    float w2 = r20*u0 + r21*u1 + r22*u2;

    int k0 = c * 3;
    store_el(Xp, b, n, k0+0, v0); store_el(Xp, b, n, k0+1, v1); store_el(Xp, b, n, k0+2, v2);
    store_el(Yp, b, n, k0+0, w0); store_el(Yp, b, n, k0+1, w1); store_el(Yp, b, n, k0+2, w2);
    if (c == CC) {  // zero the K pad 99..127 (don't rely on ws poison encoding)
        for (int k = 99; k < 128; ++k) { store_el(Xp, b, n, k, 0.f); store_el(Yp, b, n, k, 0.f); }
    }
    atomicAdd(&xn[b*NN + n], v0*v0 + v1*v1 + v2*v2);
    atomicAdd(&yn[b*NN + n], w0*w0 + w1*w1 + w2*w2);
}

// ---------------- gram: 128x128 tile / block, 4 waves 2x2, no LDS staging ----
__global__ __launch_bounds__(256) void gram_kernel(
    const __hip_bfloat16* __restrict__ Xp, const __hip_bfloat16* __restrict__ Yp,
    const float* __restrict__ xn, const float* __restrict__ yn,
    float* __restrict__ out)
{
    __shared__ float red[4];
    int b   = blockIdx.z;
    int tM  = blockIdx.x;         // col tile (Y)
    int tN  = blockIdx.y;         // row tile (X)
    int tid = threadIdx.x;
    int wid = tid >> 6, lane = tid & 63;
    int wr = wid >> 1, wc = wid & 1;
    int q = lane >> 4, cl = lane & 15;

    f32x4 acc[4][4] = {};
    #pragma unroll
    for (int kb = 0; kb < 4; ++kb) {
        short8 a[4], bb[4];
        #pragma unroll
        for (int fm = 0; fm < 4; ++fm) {
            int n16 = tN*8 + wr*4 + fm;
            a[fm] = ((const short8*)(Xp + chunk_off(b, n16, kb)))[lane];
        }
        #pragma unroll
        for (int fn = 0; fn < 4; ++fn) {
            int m16 = tM*8 + wc*4 + fn;
            bb[fn] = ((const short8*)(Yp + chunk_off(b, m16, kb)))[lane];
        }
        #pragma unroll
        for (int fm = 0; fm < 4; ++fm)
            #pragma unroll
            for (int fn = 0; fn < 4; ++fn)
                acc[fm][fn] = __builtin_amdgcn_mfma_f32_16x16x32_bf16(
                    a[fm], bb[fn], acc[fm][fn], 0, 0, 0);
    }

    int rowb = tN*128 + wr*64;
    int colb = tM*128 + wc*64;
    float ynv[4];
    #pragma unroll
    for (int fn = 0; fn < 4; ++fn) ynv[fn] = yn[b*NN + colb + fn*16 + cl];

    float lsum = 0.f;
    #pragma unroll
    for (int fm = 0; fm < 4; ++fm) {
        #pragma unroll
        for (int r = 0; r < 4; ++r) {
            int row = rowb + fm*16 + q*4 + r;
            float xv = xn[b*NN + row];
            size_t obase = 1 + ((size_t)(b*NN + row)) * NN + colb;
            #pragma unroll
            for (int fn = 0; fn < 4; ++fn) {
                float sq = fmaxf(xv + ynv[fn] - 2.f * acc[fm][fn][r], 0.f);
                float g = __expf(-sq * 0.005f);
                g = (g > 0.1f) ? g : 0.f;
                __builtin_nontemporal_store(g, &out[obase + fn*16 + cl]);
                lsum += g;
            }
        }
    }

    #pragma unroll
    for (int off = 32; off > 0; off >>= 1) lsum += __shfl_down(lsum, off, 64);
    if (lane == 0) red[wid] = lsum;
    __syncthreads();
    if (tid == 0) atomicAdd(out, red[0] + red[1] + red[2] + red[3]);
}

extern "C" void kernel_launch(void* const* d_in, const int* in_sizes, int n_in,
                              void* d_out, int out_size, void* d_ws, size_t ws_size,
                              hipStream_t stream) {
    const float* pc1   = (const float*)d_in[0];
    const float* pc2   = (const float*)d_in[1];
    const float* xfeat = (const float*)d_in[2];
    const float* yfeat = (const float*)d_in[3];
    const float* quat  = (const float*)d_in[4];
    float* out = (float*)d_out;

    __hip_bfloat16* Xp = (__hip_bfloat16*)d_ws;                     // 2 MB
    __hip_bfloat16* Yp = Xp + (size_t)BB * 256 * 4 * 512;           // 2 MB
    float* xn = (float*)(Yp + (size_t)BB * 256 * 4 * 512);          // 32 KB
    float* yn = xn + (size_t)BB * NN;                               // 32 KB

    zero_kernel<<<(BB*NN + 255)/256, 256, 0, stream>>>(xn, yn, out);
    prep_kernel<<<(BB*NN*(CC+1) + 255)/256, 256, 0, stream>>>(
        pc1, pc2, xfeat, yfeat, quat, Xp, Yp, xn, yn);
    dim3 grid(NN/128, NN/128, BB);
    gram_kernel<<<grid, 256, 0, stream>>>(Xp, Yp, xn, yn, out);
}

// Round 11
// 191.135 us; speedup vs baseline: 1.5503x; 1.2635x over previous
//
#include <hip/hip_runtime.h>
#include <hip/hip_bf16.h>

#define BB 2
#define NN 4096
#define CC 32

typedef __attribute__((ext_vector_type(8))) short short8;
typedef __attribute__((ext_vector_type(4))) float f32x4;

// 16-byte store type with only 4-byte alignment (out+1 is never 16B-aligned;
// AMD global_store_dwordx4 requires only dword alignment)
struct __attribute__((aligned(4))) f4a { float a, b, c, d; };

// Panel layout (bf16): per (b, n16, kb) a 1024B chunk; element (r=n&15,
// ks=(k>>3)&3, kk=k&7) at short offset (ks*16+r)*8+kk.
// MFMA fragment load: lane l reads 16B at chunk + l*16 (fully coalesced).
__device__ __forceinline__ size_t chunk_off(int b, int n16, int kb) {
    return (((size_t)b * 256 + n16) * 4 + kb) * 512;
}

__device__ __forceinline__ void store_el(__hip_bfloat16* P, int b, int n, int k, float v) {
    int kb = k >> 5, ks = (k >> 3) & 3, kk = k & 7;
    size_t off = chunk_off(b, n >> 4, kb) + (size_t)((ks * 16 + (n & 15)) * 8 + kk);
    P[off] = __float2bfloat16(v);
}

// ---------------- prep: thread per (channel, b, n); no atomics --------------
__global__ __launch_bounds__(256) void prep_kernel(
    const float* __restrict__ pc1, const float* __restrict__ pc2,
    const float* __restrict__ xfeat, const float* __restrict__ yfeat,
    const float* __restrict__ quat,
    __hip_bfloat16* __restrict__ Xp, __hip_bfloat16* __restrict__ Yp,
    float* __restrict__ px, float* __restrict__ py)
{
    int idx = blockIdx.x * 256 + threadIdx.x;
    if (idx >= BB * NN * (CC + 1)) return;
    int c = idx / (BB * NN);          // slowest: channel -> n stays coalesced
    int rem = idx - c * (BB * NN);
    int b = rem / NN, n = rem % NN;

    float qx = quat[b*4+0], qy = quat[b*4+1], qz = quat[b*4+2], qw = quat[b*4+3];
    float qi = rsqrtf(qx*qx + qy*qy + qz*qz + qw*qw);
    qx *= qi; qy *= qi; qz *= qi; qw *= qi;
    float r00 = 1.f-2.f*(qy*qy+qz*qz), r01 = 2.f*(qx*qy-qz*qw), r02 = 2.f*(qx*qz+qy*qw);
    float r10 = 2.f*(qx*qy+qz*qw), r11 = 1.f-2.f*(qx*qx+qz*qz), r12 = 2.f*(qy*qz-qx*qw);
    float r20 = 2.f*(qx*qz-qy*qw), r21 = 2.f*(qy*qz+qx*qw), r22 = 1.f-2.f*(qx*qx+qy*qy);

    float v0, v1, v2, u0, u1, u2;
    if (c == 0) {
        v0 = pc1[(b*3+0)*NN + n]; v1 = pc1[(b*3+1)*NN + n]; v2 = pc1[(b*3+2)*NN + n];
        u0 = pc2[(b*3+0)*NN + n]; u1 = pc2[(b*3+1)*NN + n]; u2 = pc2[(b*3+2)*NN + n];
    } else {
        size_t base = ((size_t)(b*CC + (c-1)) * 3) * NN + n;
        v0 = xfeat[base]; v1 = xfeat[base + NN]; v2 = xfeat[base + 2*NN];
        u0 = yfeat[base]; u1 = yfeat[base + NN]; u2 = yfeat[base + 2*NN];
    }
    float w0 = r00*u0 + r01*u1 + r02*u2;
    float w1 = r10*u0 + r11*u1 + r12*u2;
    float w2 = r20*u0 + r21*u1 + r22*u2;

    int k0 = c * 3;
    store_el(Xp, b, n, k0+0, v0); store_el(Xp, b, n, k0+1, v1); store_el(Xp, b, n, k0+2, v2);
    store_el(Yp, b, n, k0+0, w0); store_el(Yp, b, n, k0+1, w1); store_el(Yp, b, n, k0+2, w2);
    if (c == CC) {  // zero K pad 99..127
        for (int k = 99; k < 128; ++k) { store_el(Xp, b, n, k, 0.f); store_el(Yp, b, n, k, 0.f); }
    }
    int pidx = b * NN + n;
    px[c * (BB*NN) + pidx] = v0*v0 + v1*v1 + v2*v2;
    py[c * (BB*NN) + pidx] = w0*w0 + w1*w1 + w2*w2;
}

// ---------------- reduce: sum 33 partials per point; zero out[0] ------------
__global__ __launch_bounds__(256) void reduce_kernel(
    const float* __restrict__ px, const float* __restrict__ py,
    float* __restrict__ xn, float* __restrict__ yn, float* __restrict__ out)
{
    int i = blockIdx.x * 256 + threadIdx.x;
    if (i >= BB * NN) return;
    float sx = 0.f, sy = 0.f;
    #pragma unroll
    for (int c = 0; c <= CC; ++c) { sx += px[c*(BB*NN) + i]; sy += py[c*(BB*NN) + i]; }
    xn[i] = sx; yn[i] = sy;
    if (i == 0) out[0] = 0.f;
}

// ---------------- gram: 128x128/block, swapped-MFMA for row-major f4 stores -
__global__ __launch_bounds__(256) void gram_kernel(
    const __hip_bfloat16* __restrict__ Xp, const __hip_bfloat16* __restrict__ Yp,
    const float* __restrict__ xn, const float* __restrict__ yn,
    float* __restrict__ out)
{
    __shared__ float red[4];
    // XCD-chunked swizzle (2048 = 8 XCD * 256): consecutive work per XCD ->
    // col-adjacent tiles of a row band share L2 -> boundary sectors merge.
    int bid = blockIdx.x;
    int work = (bid & 7) * 256 + (bid >> 3);
    int b  = work >> 10;
    int rem = work & 1023;
    int tN = rem >> 5;            // row tile (X)
    int tM = rem & 31;            // col tile (Y)

    int tid = threadIdx.x;
    int wid = tid >> 6, lane = tid & 63;
    int wr = wid >> 1, wc = wid & 1;
    int q = lane >> 4, cl = lane & 15;

    // acc[i][j] = mfma(y_frag[i], x_frag[j]) -> D[y-idx][x-idx]:
    // gram row = j*16 + (lane&15), gram col = i*16 + q*4 + reg  (4 consecutive!)
    f32x4 acc[4][4] = {};
    #pragma unroll
    for (int kb = 0; kb < 4; ++kb) {
        short8 yfr[4], xfr[4];
        #pragma unroll
        for (int i = 0; i < 4; ++i)
            yfr[i] = ((const short8*)(Yp + chunk_off(b, tM*8 + wc*4 + i, kb)))[lane];
        #pragma unroll
        for (int j = 0; j < 4; ++j)
            xfr[j] = ((const short8*)(Xp + chunk_off(b, tN*8 + wr*4 + j, kb)))[lane];
        #pragma unroll
        for (int i = 0; i < 4; ++i)
            #pragma unroll
            for (int j = 0; j < 4; ++j)
                acc[i][j] = __builtin_amdgcn_mfma_f32_16x16x32_bf16(
                    yfr[i], xfr[j], acc[i][j], 0, 0, 0);
    }

    int rowb = tN*128 + wr*64;
    int colb = tM*128 + wc*64;
    float lsum = 0.f;
    #pragma unroll
    for (int j = 0; j < 4; ++j) {
        int row = rowb + j*16 + cl;
        float xv = xn[b*NN + row];
        size_t obase = 1 + (size_t)(b*NN + row) * NN;
        #pragma unroll
        for (int i = 0; i < 4; ++i) {
            int col0 = colb + i*16 + q*4;
            f32x4 yv = *(const f32x4*)(yn + b*NN + col0);   // 16B-aligned
            float g[4];
            #pragma unroll
            for (int r = 0; r < 4; ++r) {
                float sq = fmaxf(xv + yv[r] - 2.f * acc[i][j][r], 0.f);
                float e = __expf(-sq * 0.005f);
                g[r] = (e > 0.1f) ? e : 0.f;
                lsum += g[r];
            }
            f4a t; t.a = g[0]; t.b = g[1]; t.c = g[2]; t.d = g[3];
            *(f4a*)(out + obase + col0) = t;                // dwordx4, 4B-aligned
        }
    }

    #pragma unroll
    for (int off = 32; off > 0; off >>= 1) lsum += __shfl_down(lsum, off, 64);
    if (lane == 0) red[wid] = lsum;
    __syncthreads();
    if (tid == 0) atomicAdd(out, red[0] + red[1] + red[2] + red[3]);
}

extern "C" void kernel_launch(void* const* d_in, const int* in_sizes, int n_in,
                              void* d_out, int out_size, void* d_ws, size_t ws_size,
                              hipStream_t stream) {
    const float* pc1   = (const float*)d_in[0];
    const float* pc2   = (const float*)d_in[1];
    const float* xfeat = (const float*)d_in[2];
    const float* yfeat = (const float*)d_in[3];
    const float* quat  = (const float*)d_in[4];
    float* out = (float*)d_out;

    __hip_bfloat16* Xp = (__hip_bfloat16*)d_ws;                     // 2 MB
    __hip_bfloat16* Yp = Xp + (size_t)BB * 256 * 4 * 512;           // 2 MB
    float* xn = (float*)(Yp + (size_t)BB * 256 * 4 * 512);          // 32 KB
    float* yn = xn + (size_t)BB * NN;                               // 32 KB
    float* px = yn + (size_t)BB * NN;                               // 1.06 MB
    float* py = px + (size_t)(CC + 1) * BB * NN;                    // 1.06 MB

    prep_kernel<<<(BB*NN*(CC+1) + 255)/256, 256, 0, stream>>>(
        pc1, pc2, xfeat, yfeat, quat, Xp, Yp, px, py);
    reduce_kernel<<<(BB*NN + 255)/256, 256, 0, stream>>>(px, py, xn, yn, out);
    gram_kernel<<<2048, 256, 0, stream>>>(Xp, Yp, xn, yn, out);
}

// Round 14
// 179.104 us; speedup vs baseline: 1.6544x; 1.0672x over previous
//
#include <hip/hip_runtime.h>
#include <hip/hip_bf16.h>

#define BB 2
#define NN 4096
#define CC 32
#define PG 16   // 16 k-groups of 8 -> K=128

typedef __attribute__((ext_vector_type(8))) short short8;
typedef __attribute__((ext_vector_type(4))) float f32x4;

// 16-byte store type with only 4-byte alignment (out+1 is never 16B-aligned;
// AMD global_store_dwordx4 requires only dword alignment)
struct __attribute__((aligned(4))) f4a { float a, b, c, d; };

__device__ __forceinline__ unsigned short f2bf(float v) {
    return __builtin_bit_cast(unsigned short, __float2bfloat16(v));
}

// Panel layout (bf16): per (b, n16, kb) a 1024B chunk; element (r=n&15,
// ks=(k>>3)&3, kk=k&7) at short offset (ks*16+r)*8+kk.
// MFMA fragment load: lane l reads 16B at chunk + l*16 (fully coalesced).
__device__ __forceinline__ size_t chunk_off(int b, int n16, int kb) {
    return (((size_t)b * 256 + n16) * 4 + kb) * 512;
}

// ---------------- prep: thread per (g, b, n); one 16B store per panel -------
__global__ __launch_bounds__(256) void prep_kernel(
    const float* __restrict__ pc1, const float* __restrict__ pc2,
    const float* __restrict__ xfeat, const float* __restrict__ yfeat,
    const float* __restrict__ quat,
    __hip_bfloat16* __restrict__ Xp, __hip_bfloat16* __restrict__ Yp,
    float* __restrict__ px, float* __restrict__ py)
{
    int idx = blockIdx.x * 256 + threadIdx.x;   // PG*BB*NN = 131072
    if (idx >= PG * BB * NN) return;
    int g = idx >> 13;            // k-group, slowest -> n stays coalesced
    int rem = idx & 8191;
    int b = rem >> 12;
    int n = rem & 4095;
    int k0 = g * 8;

    float qx = quat[b*4+0], qy = quat[b*4+1], qz = quat[b*4+2], qw = quat[b*4+3];
    float qi = rsqrtf(qx*qx + qy*qy + qz*qz + qw*qw);
    qx *= qi; qy *= qi; qz *= qi; qw *= qi;
    float r00 = 1.f-2.f*(qy*qy+qz*qz), r01 = 2.f*(qx*qy-qz*qw), r02 = 2.f*(qx*qz+qy*qw);
    float r10 = 2.f*(qx*qy+qz*qw), r11 = 1.f-2.f*(qx*qx+qz*qz), r12 = 2.f*(qy*qz-qx*qw);
    float r20 = 2.f*(qx*qz-qy*qw), r21 = 2.f*(qy*qz+qx*qw), r22 = 1.f-2.f*(qx*qx+qy*qy);

    unsigned short hx[8], hy[8];
    float sx = 0.f, sy = 0.f;
    #pragma unroll
    for (int t = 0; t < 8; ++t) {       // t static -> no runtime-indexed arrays
        int k = k0 + t;
        float vx = 0.f, wy = 0.f;
        if (k < 99) {
            int c = k / 3, comp = k - 3*c;
            const float* xsrc = (c == 0)
                ? (pc1 + (size_t)(b*3 + comp) * NN)
                : (xfeat + ((size_t)(b*CC + c-1)*3 + comp) * NN);
            vx = xsrc[n];
            const float* ybase = (c == 0)
                ? (pc2 + (size_t)b*3*NN)
                : (yfeat + (size_t)(b*CC + c-1)*3*NN);
            float u0 = ybase[n], u1 = ybase[NN + n], u2 = ybase[2*NN + n];
            wy = (comp == 0) ? r00*u0 + r01*u1 + r02*u2
               : (comp == 1) ? r10*u0 + r11*u1 + r12*u2
                             : r20*u0 + r21*u1 + r22*u2;
        }
        sx += vx*vx; sy += wy*wy;
        hx[t] = f2bf(vx);
        hy[t] = f2bf(wy);
    }

    int kb = g >> 2, ks = g & 3;
    size_t off = chunk_off(b, n >> 4, kb) + (size_t)(ks*16 + (n & 15)) * 8;
    short8 vx8, vy8;
    #pragma unroll
    for (int t = 0; t < 8; ++t) { vx8[t] = (short)hx[t]; vy8[t] = (short)hy[t]; }
    *(short8*)(Xp + off) = vx8;         // one 16B aligned store
    *(short8*)(Yp + off) = vy8;         // one 16B aligned store

    int pidx = g * (BB*NN) + b*NN + n;
    px[pidx] = sx; py[pidx] = sy;
}

// ---------------- reduce: sum 16 partials per point; zero out[0] ------------
__global__ __launch_bounds__(256) void reduce_kernel(
    const float* __restrict__ px, const float* __restrict__ py,
    float* __restrict__ xn, float* __restrict__ yn, float* __restrict__ out)
{
    int i = blockIdx.x * 256 + threadIdx.x;
    if (i >= BB * NN) return;
    float sx = 0.f, sy = 0.f;
    #pragma unroll
    for (int g = 0; g < PG; ++g) { sx += px[g*(BB*NN) + i]; sy += py[g*(BB*NN) + i]; }
    xn[i] = sx; yn[i] = sy;
    if (i == 0) out[0] = 0.f;
}

// ---------------- gram: 128x128/block, swapped-MFMA for row-major f4 stores -
__global__ __launch_bounds__(256) void gram_kernel(
    const __hip_bfloat16* __restrict__ Xp, const __hip_bfloat16* __restrict__ Yp,
    const float* __restrict__ xn, const float* __restrict__ yn,
    float* __restrict__ out)
{
    __shared__ float red[4];
    // XCD-chunked swizzle (2048 = 8 XCD * 256): consecutive work per XCD ->
    // col-adjacent tiles of a row band share L2 -> boundary sectors merge.
    int bid = blockIdx.x;
    int work = (bid & 7) * 256 + (bid >> 3);
    int b  = work >> 10;
    int rem = work & 1023;
    int tN = rem >> 5;            // row tile (X)
    int tM = rem & 31;            // col tile (Y)

    int tid = threadIdx.x;
    int wid = tid >> 6, lane = tid & 63;
    int wr = wid >> 1, wc = wid & 1;
    int q = lane >> 4, cl = lane & 15;

    // acc[i][j] = mfma(y_frag[i], x_frag[j]) -> D[y-idx][x-idx]:
    // gram row = j*16 + (lane&15), gram col = i*16 + q*4 + reg  (4 consecutive!)
    f32x4 acc[4][4] = {};
    #pragma unroll
    for (int kb = 0; kb < 4; ++kb) {
        short8 yfr[4], xfr[4];
        #pragma unroll
        for (int i = 0; i < 4; ++i)
            yfr[i] = ((const short8*)(Yp + chunk_off(b, tM*8 + wc*4 + i, kb)))[lane];
        #pragma unroll
        for (int j = 0; j < 4; ++j)
            xfr[j] = ((const short8*)(Xp + chunk_off(b, tN*8 + wr*4 + j, kb)))[lane];
        #pragma unroll
        for (int i = 0; i < 4; ++i)
            #pragma unroll
            for (int j = 0; j < 4; ++j)
                acc[i][j] = __builtin_amdgcn_mfma_f32_16x16x32_bf16(
                    yfr[i], xfr[j], acc[i][j], 0, 0, 0);
    }

    int rowb = tN*128 + wr*64;
    int colb = tM*128 + wc*64;
    float lsum = 0.f;
    #pragma unroll
    for (int j = 0; j < 4; ++j) {
        int row = rowb + j*16 + cl;
        float xv = xn[b*NN + row];
        size_t obase = 1 + (size_t)(b*NN + row) * NN;
        #pragma unroll
        for (int i = 0; i < 4; ++i) {
            int col0 = colb + i*16 + q*4;
            f32x4 yv = *(const f32x4*)(yn + b*NN + col0);   // 16B-aligned
            float g[4];
            #pragma unroll
            for (int r = 0; r < 4; ++r) {
                float sq = fmaxf(xv + yv[r] - 2.f * acc[i][j][r], 0.f);
                float e = __expf(-sq * 0.005f);
                g[r] = (e > 0.1f) ? e : 0.f;
                lsum += g[r];
            }
            f4a t; t.a = g[0]; t.b = g[1]; t.c = g[2]; t.d = g[3];
            *(f4a*)(out + obase + col0) = t;                // dwordx4, 4B-aligned
        }
    }

    #pragma unroll
    for (int off = 32; off > 0; off >>= 1) lsum += __shfl_down(lsum, off, 64);
    if (lane == 0) red[wid] = lsum;
    __syncthreads();
    if (tid == 0) atomicAdd(out, red[0] + red[1] + red[2] + red[3]);
}

extern "C" void kernel_launch(void* const* d_in, const int* in_sizes, int n_in,
                              void* d_out, int out_size, void* d_ws, size_t ws_size,
                              hipStream_t stream) {
    const float* pc1   = (const float*)d_in[0];
    const float* pc2   = (const float*)d_in[1];
    const float* xfeat = (const float*)d_in[2];
    const float* yfeat = (const float*)d_in[3];
    const float* quat  = (const float*)d_in[4];
    float* out = (float*)d_out;

    __hip_bfloat16* Xp = (__hip_bfloat16*)d_ws;                     // 2 MB
    __hip_bfloat16* Yp = Xp + (size_t)BB * 256 * 4 * 512;           // 2 MB
    float* xn = (float*)(Yp + (size_t)BB * 256 * 4 * 512);          // 32 KB
    float* yn = xn + (size_t)BB * NN;                               // 32 KB
    float* px = yn + (size_t)BB * NN;                               // 512 KB
    float* py = px + (size_t)PG * BB * NN;                          // 512 KB

    prep_kernel<<<(PG*BB*NN + 255)/256, 256, 0, stream>>>(
        pc1, pc2, xfeat, yfeat, quat, Xp, Yp, px, py);
    reduce_kernel<<<(BB*NN + 255)/256, 256, 0, stream>>>(px, py, xn, yn, out);
    gram_kernel<<<2048, 256, 0, stream>>>(Xp, Yp, xn, yn, out);
}